// Round 2
// baseline (309.462 us; speedup 1.0000x reference)
//
#include <hip/hip_runtime.h>
#include <cmath>

typedef float    float4_t __attribute__((ext_vector_type(4)));
typedef float    f32x16   __attribute__((ext_vector_type(16)));
typedef __bf16   bf16x8   __attribute__((ext_vector_type(8)));
typedef unsigned uint4_v  __attribute__((ext_vector_type(4)));
typedef unsigned short u16;

// V^T row stride (u16 units): 2048 + 64 pad breaks the 4KB L1-set aliasing of
// the 32-row strided fragment reads in mqa_attn.
#define VSTR 2112

// fp32 -> bf16 round-to-nearest-even
__device__ __forceinline__ u16 f2bf(float f) {
    unsigned u = __float_as_uint(f);
    u += 0x7fffu + ((u >> 16) & 1u);
    return (u16)(u >> 16);
}

// v_cvt_pk_bf16_f32: lo = bf16(a), hi = bf16(b)
__device__ __forceinline__ unsigned cvtpk(float a, float b) {
    unsigned r;
    asm("v_cvt_pk_bf16_f32 %0, %1, %2" : "=v"(r) : "v"(a), "v"(b));
    return r;
}
// v_permlane32_swap_b32: a[32..63] <-> b[0..31]
__device__ __forceinline__ void pl32swap(unsigned& a, unsigned& b) {
    asm volatile("v_permlane32_swap_b32 %0, %1" : "+v"(a), "+v"(b));
}

// async global->LDS, 16B per lane. LDS dest must be wave-uniform base + lane*16.
#define GLOAD_LDS16(g, l)                                              \
    __builtin_amdgcn_global_load_lds(                                  \
        (__attribute__((address_space(1))) void*)(g),                  \
        (__attribute__((address_space(3))) void*)(l), 16, 0, 0)

// Chunk swizzle for the GEMM LDS tiles (unchanged): global chunk c of row r is
// stored at LDS chunk (c + (r>>1))&3; keeps b128 frag reads ~conflict-free.
__device__ __forceinline__ int sw_st(int cs, int row) { return ((cs - (row >> 1)) & 3) * 8; }
__device__ __forceinline__ int sw_rd(int ch, int row) { return (((ch + (row >> 1)) & 3)) * 8; }

// ---------------- merged cast fp32 -> bf16 for all 5 tensors ----------------
__global__ __launch_bounds__(256) void cast_all(const float* __restrict__ x,
                                                const float* __restrict__ wq,
                                                const float* __restrict__ wk,
                                                const float* __restrict__ wv,
                                                const float* __restrict__ wo,
                                                u16* __restrict__ xb, u16* __restrict__ wqb,
                                                u16* __restrict__ wkb, u16* __restrict__ wvb,
                                                u16* __restrict__ wob) {
    const int b = blockIdx.x;
    const float* src;
    u16* dst;
    int i;
    if (b < 4096)      { src = x;  dst = xb;  i = b * 256 + threadIdx.x; }
    else if (b < 8192) { src = wq; dst = wqb; i = (b - 4096) * 256 + threadIdx.x; }
    else if (b < 8448) { src = wk; dst = wkb; i = (b - 8192) * 256 + threadIdx.x; }
    else if (b < 8704) { src = wv; dst = wvb; i = (b - 8448) * 256 + threadIdx.x; }
    else               { src = wo; dst = wob; i = (b - 8704) * 256 + threadIdx.x; }
    float4 f = ((const float4*)src)[i];
    ushort4 r;
    r.x = f2bf(f.x); r.y = f2bf(f.y); r.z = f2bf(f.z); r.w = f2bf(f.w);
    ((ushort4*)dst)[i] = r;
}

// ================= GEMM core (A @ B^T, 64x128 tile, BK=64, swizzled) ========
// 2-phase double-buffered staging: issue next tile's global_load_lds before
// current compute; ONE barrier per K-step. 48KB LDS, 256 threads = 4 waves.
template <typename EPI>
__device__ __forceinline__ void gemm_core(const u16* __restrict__ A,
                                          const u16* __restrict__ B,
                                          int K, int bm, int bn, EPI epi) {
    __shared__ __align__(16) u16 As[2][2 * 64 * 32];
    __shared__ __align__(16) u16 Bs[2][2 * 128 * 32];
    const int tid  = threadIdx.x;
    const int lane = tid & 63, wave = tid >> 6;
    const int quad = lane >> 4, l16 = lane & 15;

    float4_t acc[4][2] = {};

    auto stage = [&](int k0, int buf) {
#pragma unroll
        for (int i = 0; i < 2; ++i) {
            const int slot = i * 256 + tid;
            const int ksb = slot >> 8, win = slot & 255;
            const int row = win >> 2;
            GLOAD_LDS16(A + (size_t)(bm + row) * K + k0 + ksb * 32 + sw_st(win & 3, row),
                        &As[buf][slot * 8]);
        }
#pragma unroll
        for (int i = 0; i < 4; ++i) {
            const int slot = i * 256 + tid;
            const int ksb = slot >> 9, win = slot & 511;
            const int row = win >> 2;
            GLOAD_LDS16(B + (size_t)(bn + row) * K + k0 + ksb * 32 + sw_st(win & 3, row),
                        &Bs[buf][slot * 8]);
        }
    };

    stage(0, 0);
    __syncthreads();
    int cur = 0;
    for (int k0 = 0; k0 < K; k0 += 64) {
        if (k0 + 64 < K) stage(k0 + 64, cur ^ 1);

        bf16x8 af[2][4], bfr[2][2];
#pragma unroll
        for (int ksb = 0; ksb < 2; ++ksb) {
#pragma unroll
            for (int mi = 0; mi < 4; ++mi) {
                const int rw = mi * 16 + l16;
                af[ksb][mi] = *(const bf16x8*)&As[cur][ksb * 2048 + rw * 32 + sw_rd(quad, rw)];
            }
#pragma unroll
            for (int ni = 0; ni < 2; ++ni) {
                const int rw = wave * 32 + ni * 16 + l16;
                bfr[ksb][ni] = *(const bf16x8*)&Bs[cur][ksb * 4096 + rw * 32 + sw_rd(quad, rw)];
            }
        }
#pragma unroll
        for (int mi = 0; mi < 4; ++mi)
#pragma unroll
            for (int ni = 0; ni < 2; ++ni) {
                acc[mi][ni] = __builtin_amdgcn_mfma_f32_16x16x32_bf16(
                    af[0][mi], bfr[0][ni], acc[mi][ni], 0, 0, 0);
                acc[mi][ni] = __builtin_amdgcn_mfma_f32_16x16x32_bf16(
                    af[1][mi], bfr[1][ni], acc[mi][ni], 0, 0, 0);
            }
        __syncthreads();   // drains next-tile gload_lds (vmcnt) + read hazard
        cur ^= 1;
    }

#pragma unroll
    for (int mi = 0; mi < 4; ++mi) {
        const int row = bm + mi * 16 + quad * 4;
#pragma unroll
        for (int ni = 0; ni < 2; ++ni) {
            const int col = bn + wave * 32 + ni * 16 + l16;
#pragma unroll
            for (int r = 0; r < 4; ++r) epi(row + r, col, acc[mi][ni][r]);
        }
    }
}

// Fused QKV projection: B rows = [Wq(2048) | Wk(128) | Wv(128)], N=2304.
// Q gets (1/sqrt(128))*log2(e) folded in (attention uses exp2).
__global__ __launch_bounds__(256) void gemm_qkv(const u16* __restrict__ A,
                                                const u16* __restrict__ B,
                                                u16* __restrict__ qb,
                                                u16* __restrict__ kb,
                                                u16* __restrict__ vtb) {
    gemm_core(A, B, 2048, blockIdx.x * 64, blockIdx.y * 128,
              [=](int row, int col, float v) {
                  if (col < 2048)
                      qb[(size_t)row * 2048 + col] = f2bf(v * 0.1275174313451427f);
                  else if (col < 2176)
                      kb[(size_t)row * 128 + (col - 2048)] = f2bf(v);
                  else
                      vtb[(size_t)(col - 2176) * VSTR + row] = f2bf(v);
              });
}

__global__ __launch_bounds__(256) void gemm_out(const u16* __restrict__ A,
                                                const u16* __restrict__ B,
                                                float* __restrict__ C) {
    gemm_core(A, B, 2048, blockIdx.x * 64, blockIdx.y * 128,
              [=](int row, int col, float v) {
                  C[(size_t)row * 2048 + col] = v;
              });
}

// ---------------- MQA flash attention, split-K=2, 64 keys/step --------------
// LDS-FREE: K (256KB/half) and V (256KB/half) are shared by all 256 blocks of
// a key-half -> fully L2/L3-resident. Staging them through LDS was pure
// overhead (barriers, bank conflicts, 2-wave/SIMD lockstep). Fragments are
// read straight from global (16B/lane, L1/L2 hits); ZERO barriers -> waves
// free-run and the compiler pipelines QK(s+1) under PV(s).
// 32x32x16 MFMA, swapped QK^T (A=K, B=Q => S^T col = query = lane&31);
// P stays in registers via v_cvt_pk_bf16_f32 + v_permlane32_swap_b32 (T12).
// Block = 128 q x 1 head x 1 key-half; grid (16,16,2). Deferred softmax:
// P = exp2(s) (Q pre-scaled); fp32 partials + Lsum, normalized in combine.
__global__ __launch_bounds__(256) void mqa_attn(const u16* __restrict__ Q,
                                                const u16* __restrict__ Kmat,
                                                const u16* __restrict__ Vt,
                                                float* __restrict__ Oacc0,
                                                float* __restrict__ Oacc1,
                                                float* __restrict__ Lsum) {
    const int tid  = threadIdx.x;
    const int wave = tid >> 6, lane = tid & 63;
    const int l31 = lane & 31, hi = lane >> 5;
    const int h     = blockIdx.y;
    const int ksp   = blockIdx.z;
    const int qbase = blockIdx.x * 128 + wave * 32;
    const int kbase = ksp * 1024;

    // Q as B-operand frags for swapped QK: lane holds Q[q=l31][c*16 + hi*8 + j]
    bf16x8 qf[8];
    {
        const u16* qptr = Q + (size_t)(qbase + l31) * 2048 + h * 128 + hi * 8;
#pragma unroll
        for (int c = 0; c < 8; ++c) qf[c] = *(const bf16x8*)(qptr + c * 16);
    }

    f32x16 acc[4];
#pragma unroll
    for (int dt = 0; dt < 4; ++dt) acc[dt] = (f32x16)(0.0f);
    float lsum = 0.f;

#pragma unroll 2
    for (int s = 0; s < 16; ++s) {
        const int k0 = kbase + s * 64;

        // ---- S^T = K Q^T per 32-key tile; P = exp2(S) packed in-register ----
        bf16x8 pa[4];  // PV A-frags, key chunks of 16
#pragma unroll
        for (int kt = 0; kt < 2; ++kt) {
            f32x16 sv = (f32x16)(0.0f);
            const u16* kp = Kmat + (size_t)(k0 + kt * 32 + l31) * 128 + hi * 8;
#pragma unroll
            for (int c = 0; c < 8; ++c) {
                bf16x8 kf = *(const bf16x8*)(kp + c * 16);
                sv = __builtin_amdgcn_mfma_f32_32x32x16_bf16(kf, qf[c], sv, 0, 0, 0);
            }
            // lane holds S^T[key=(r&3)+8*(r>>2)+4*hi][q=l31]
            float e[16];
#pragma unroll
            for (int r = 0; r < 16; ++r) {
                e[r] = exp2f(sv[r]);
                lsum += e[r];
            }
            // pack to bf16 + permlane32_swap -> A-frag keys ascending
#pragma unroll
            for (int half = 0; half < 2; ++half) {
                unsigned a0 = cvtpk(e[half * 8 + 0], e[half * 8 + 1]);
                unsigned a1 = cvtpk(e[half * 8 + 2], e[half * 8 + 3]);
                unsigned b0 = cvtpk(e[half * 8 + 4], e[half * 8 + 5]);
                unsigned b1 = cvtpk(e[half * 8 + 6], e[half * 8 + 7]);
                pl32swap(a0, b0);
                pl32swap(a1, b1);
                uint4_v w = {a0, a1, b0, b1};
                pa[kt * 2 + half] = __builtin_bit_cast(bf16x8, w);
            }
        }

        // ---- O += P V : 16 MFMA, 4 independent dt chains, V^T direct ----
#pragma unroll
        for (int dt = 0; dt < 4; ++dt) {
            const u16* vp = Vt + (size_t)(dt * 32 + l31) * VSTR + k0 + hi * 8;
#pragma unroll
            for (int kc = 0; kc < 4; ++kc) {
                bf16x8 vf = *(const bf16x8*)(vp + kc * 16);
                acc[dt] = __builtin_amdgcn_mfma_f32_32x32x16_bf16(pa[kc], vf, acc[dt], 0, 0, 0);
            }
        }
    }

    // ---- epilogue: unnormalized fp32 partials + per-row sums ----
    float lrow = lsum + __shfl_xor(lsum, 32);
    float* __restrict__ Op = ksp ? Oacc1 : Oacc0;
    if (lane < 32) Lsum[(size_t)ksp * 32768 + h * 2048 + qbase + l31] = lrow;
#pragma unroll
    for (int dt = 0; dt < 4; ++dt)
#pragma unroll
        for (int r = 0; r < 16; ++r) {
            const int qloc = (r & 3) + 8 * (r >> 2) + 4 * hi;
            Op[((size_t)h * 2048 + qbase + qloc) * 128 + dt * 32 + l31] = acc[dt][r];
        }
}

// combine: attn[q][h*128+d] = (O0+O1)/(L0+L1), bf16. One float4 per thread.
__global__ __launch_bounds__(256) void attn_combine(const float* __restrict__ O0,
                                                    const float* __restrict__ O1,
                                                    const float* __restrict__ L,
                                                    u16* __restrict__ attn) {
    const int f = blockIdx.x * 256 + threadIdx.x;  // [0, 1M)
    const int d4 = f & 31, h = (f >> 5) & 15, q = f >> 9;
    const int li = h * 2048 + q;
    const float inv = 1.0f / (L[li] + L[32768 + li]);
    const int oi = li * 32 + d4;
    const float4 a = ((const float4*)O0)[oi];
    const float4 b = ((const float4*)O1)[oi];
    ushort4 r;
    r.x = f2bf((a.x + b.x) * inv);
    r.y = f2bf((a.y + b.y) * inv);
    r.z = f2bf((a.z + b.z) * inv);
    r.w = f2bf((a.w + b.w) * inv);
    ((ushort4*)attn)[f] = r;
}

// ---------------- orchestration ----------------
extern "C" void kernel_launch(void* const* d_in, const int* in_sizes, int n_in,
                              void* d_out, int out_size, void* d_ws, size_t ws_size,
                              hipStream_t stream) {
    const float* x  = (const float*)d_in[0];
    const float* Wq = (const float*)d_in[1];
    const float* Wk = (const float*)d_in[2];
    const float* Wv = (const float*)d_in[3];
    const float* Wo = (const float*)d_in[4];
    float* out = (float*)d_out;

    // Wqb/Wkb/Wvb contiguous: together a 2304x2048 bf16 B matrix for gemm_qkv.
    // Overlays (stream-ordered, deterministic):
    //   Oacc0: [0,16MB)  -- xb+Wqb dead after gemm_qkv
    //   Oacc1: after attn buffer -- fresh scratch; Lsum after. Peak ~59MB.
    u16* ws   = (u16*)d_ws;
    u16* xb   = ws;                        // 2048x2048 bf16
    u16* Wqb  = xb  + (4 << 20);           // 2048x2048
    u16* Wkb  = Wqb + (4 << 20);           // 128x2048
    u16* Wvb  = Wkb + (256 << 10);         // 128x2048
    u16* Wob  = Wvb + (256 << 10);         // 2048x2048
    u16* qb   = Wob + (4 << 20);           // 2048x2048 (pre-scaled)
    u16* kb   = qb  + (4 << 20);           // 2048x128
    u16* vtb  = kb  + (256 << 10);         // 128xVSTR (V^T, padded rows)
    u16* attn = vtb + (512 << 10);         // 2048x2048 bf16
    float* Oacc0 = (float*)ws;             // 16 MB
    float* Oacc1 = (float*)(attn + (4 << 20));  // 16 MB
    float* Lsum  = Oacc1 + (4 << 20);      // 2 x 32768 fp32

    cast_all<<<12800, 256, 0, stream>>>(x, Wq, Wk, Wv, Wo, xb, Wqb, Wkb, Wvb, Wob);

    gemm_qkv<<<dim3(32, 18), 256, 0, stream>>>(xb, Wqb, qb, kb, vtb);
    mqa_attn<<<dim3(16, 16, 2), 256, 0, stream>>>(qb, kb, vtb, Oacc0, Oacc1, Lsum);
    attn_combine<<<4096, 256, 0, stream>>>(Oacc0, Oacc1, Lsum, attn);
    gemm_out<<<dim3(32, 16), 256, 0, stream>>>(attn, Wob, out);
}

// Round 8
// 238.722 us; speedup vs baseline: 1.2963x; 1.2963x over previous
//
#include <hip/hip_runtime.h>
#include <cmath>

typedef float    float4_t __attribute__((ext_vector_type(4)));
typedef float    f32x16   __attribute__((ext_vector_type(16)));
typedef __bf16   bf16x8   __attribute__((ext_vector_type(8)));
typedef unsigned uint4_v  __attribute__((ext_vector_type(4)));
typedef unsigned short u16;

// V^T row stride (u16 units): 2048 + 64 pad (keeps 16B alignment: 4224B rows).
#define VSTR 2112

// fp32 -> bf16 round-to-nearest-even
__device__ __forceinline__ u16 f2bf(float f) {
    unsigned u = __float_as_uint(f);
    u += 0x7fffu + ((u >> 16) & 1u);
    return (u16)(u >> 16);
}

// v_cvt_pk_bf16_f32: lo = bf16(a), hi = bf16(b)
__device__ __forceinline__ unsigned cvtpk(float a, float b) {
    unsigned r;
    asm("v_cvt_pk_bf16_f32 %0, %1, %2" : "=v"(r) : "v"(a), "v"(b));
    return r;
}
// v_permlane32_swap_b32: a[32..63] <-> b[0..31]
__device__ __forceinline__ void pl32swap(unsigned& a, unsigned& b) {
    asm volatile("v_permlane32_swap_b32 %0, %1" : "+v"(a), "+v"(b));
}

// async global->LDS, 16B per lane. LDS dest must be wave-uniform base + lane*16.
#define GLOAD_LDS16(g, l)                                              \
    __builtin_amdgcn_global_load_lds(                                  \
        (__attribute__((address_space(1))) void*)(g),                  \
        (__attribute__((address_space(3))) void*)(l), 16, 0, 0)

// Chunk swizzle: global chunk c of row r stored at LDS chunk (c + (r>>1))&3.
// Staging picks global chunk (cs - (r>>1))&3 for LDS slot cs; frag reads use
// chunk ((ch + (r>>1))&3). Keeps b128 frag reads near the free 2-way tier.
__device__ __forceinline__ int sw_st(int cs, int row) { return ((cs - (row >> 1)) & 3) * 8; }
__device__ __forceinline__ int sw_rd(int ch, int row) { return (((ch + (row >> 1)) & 3)) * 8; }

// ---------------- merged cast fp32 -> bf16 for all 5 tensors ----------------
__global__ __launch_bounds__(256) void cast_all(const float* __restrict__ x,
                                                const float* __restrict__ wq,
                                                const float* __restrict__ wk,
                                                const float* __restrict__ wv,
                                                const float* __restrict__ wo,
                                                u16* __restrict__ xb, u16* __restrict__ wqb,
                                                u16* __restrict__ wkb, u16* __restrict__ wvb,
                                                u16* __restrict__ wob) {
    const int b = blockIdx.x;
    const float* src;
    u16* dst;
    int i;
    if (b < 4096)      { src = x;  dst = xb;  i = b * 256 + threadIdx.x; }
    else if (b < 8192) { src = wq; dst = wqb; i = (b - 4096) * 256 + threadIdx.x; }
    else if (b < 8448) { src = wk; dst = wkb; i = (b - 8192) * 256 + threadIdx.x; }
    else if (b < 8704) { src = wv; dst = wvb; i = (b - 8448) * 256 + threadIdx.x; }
    else               { src = wo; dst = wob; i = (b - 8704) * 256 + threadIdx.x; }
    float4 f = ((const float4*)src)[i];
    ushort4 r;
    r.x = f2bf(f.x); r.y = f2bf(f.y); r.z = f2bf(f.z); r.w = f2bf(f.w);
    ((ushort4*)dst)[i] = r;
}

// ================= GEMM core (A @ B^T, 64x128 tile, BK=64, swizzled) ========
// 2-phase double-buffered staging; ONE barrier per K-step. 48KB LDS, 4 waves.
template <typename EPI>
__device__ __forceinline__ void gemm_core(const u16* __restrict__ A,
                                          const u16* __restrict__ B,
                                          int K, int bm, int bn, EPI epi) {
    __shared__ __align__(16) u16 As[2][2 * 64 * 32];
    __shared__ __align__(16) u16 Bs[2][2 * 128 * 32];
    const int tid  = threadIdx.x;
    const int lane = tid & 63, wave = tid >> 6;
    const int quad = lane >> 4, l16 = lane & 15;

    float4_t acc[4][2] = {};

    auto stage = [&](int k0, int buf) {
#pragma unroll
        for (int i = 0; i < 2; ++i) {
            const int slot = i * 256 + tid;
            const int ksb = slot >> 8, win = slot & 255;
            const int row = win >> 2;
            GLOAD_LDS16(A + (size_t)(bm + row) * K + k0 + ksb * 32 + sw_st(win & 3, row),
                        &As[buf][slot * 8]);
        }
#pragma unroll
        for (int i = 0; i < 4; ++i) {
            const int slot = i * 256 + tid;
            const int ksb = slot >> 9, win = slot & 511;
            const int row = win >> 2;
            GLOAD_LDS16(B + (size_t)(bn + row) * K + k0 + ksb * 32 + sw_st(win & 3, row),
                        &Bs[buf][slot * 8]);
        }
    };

    stage(0, 0);
    __syncthreads();
    int cur = 0;
    for (int k0 = 0; k0 < K; k0 += 64) {
        if (k0 + 64 < K) stage(k0 + 64, cur ^ 1);

        bf16x8 af[2][4], bfr[2][2];
#pragma unroll
        for (int ksb = 0; ksb < 2; ++ksb) {
#pragma unroll
            for (int mi = 0; mi < 4; ++mi) {
                const int rw = mi * 16 + l16;
                af[ksb][mi] = *(const bf16x8*)&As[cur][ksb * 2048 + rw * 32 + sw_rd(quad, rw)];
            }
#pragma unroll
            for (int ni = 0; ni < 2; ++ni) {
                const int rw = wave * 32 + ni * 16 + l16;
                bfr[ksb][ni] = *(const bf16x8*)&Bs[cur][ksb * 4096 + rw * 32 + sw_rd(quad, rw)];
            }
        }
#pragma unroll
        for (int mi = 0; mi < 4; ++mi)
#pragma unroll
            for (int ni = 0; ni < 2; ++ni) {
                acc[mi][ni] = __builtin_amdgcn_mfma_f32_16x16x32_bf16(
                    af[0][mi], bfr[0][ni], acc[mi][ni], 0, 0, 0);
                acc[mi][ni] = __builtin_amdgcn_mfma_f32_16x16x32_bf16(
                    af[1][mi], bfr[1][ni], acc[mi][ni], 0, 0, 0);
            }
        __syncthreads();   // drains next-tile gload_lds (vmcnt) + read hazard
        cur ^= 1;
    }

#pragma unroll
    for (int mi = 0; mi < 4; ++mi) {
        const int row = bm + mi * 16 + quad * 4;
#pragma unroll
        for (int ni = 0; ni < 2; ++ni) {
            const int col = bn + wave * 32 + ni * 16 + l16;
#pragma unroll
            for (int r = 0; r < 4; ++r) epi(row + r, col, acc[mi][ni][r]);
        }
    }
}

// Fused QKV projection: B rows = [Wq(2048) | Wk(128) | Wv(128)], N=2304.
// Q gets (1/sqrt(128))*log2(e) folded in (attention uses exp2).
__global__ __launch_bounds__(256) void gemm_qkv(const u16* __restrict__ A,
                                                const u16* __restrict__ B,
                                                u16* __restrict__ qb,
                                                u16* __restrict__ kb,
                                                u16* __restrict__ vtb) {
    gemm_core(A, B, 2048, blockIdx.x * 64, blockIdx.y * 128,
              [=](int row, int col, float v) {
                  if (col < 2048)
                      qb[(size_t)row * 2048 + col] = f2bf(v * 0.1275174313451427f);
                  else if (col < 2176)
                      kb[(size_t)row * 128 + (col - 2048)] = f2bf(v);
                  else
                      vtb[(size_t)(col - 2176) * VSTR + row] = f2bf(v);
              });
}

__global__ __launch_bounds__(256) void gemm_out(const u16* __restrict__ A,
                                                const u16* __restrict__ B,
                                                float* __restrict__ C) {
    gemm_core(A, B, 2048, blockIdx.x * 64, blockIdx.y * 128,
              [=](int row, int col, float v) {
                  C[(size_t)row * 2048 + col] = v;
              });
}

// ---------------- MQA flash attention, split-K=2, 64 keys/step --------------
// 64 QUERIES PER WAVE (2 q-tiles share every K/V fragment read): per wave-step
// 32KB LDS read feeds 64 MFMAs (2x the arithmetic intensity of 32q/wave —
// that ratio was the r1 cap, MfmaUtil 24%). 2 waves/block, 128 threads, grid
// (16,16,2) = 2 blocks/CU (64KB LDS) = 1 wave/SIMD; __launch_bounds__(128,1)
// gives the 512-VGPR budget the ~290-reg working set needs (no spill).
// 32x32x16 MFMA, swapped QK^T (A=K, B=Q => S^T col = query = lane&31);
// P in registers via v_cvt_pk_bf16_f32 + v_permlane32_swap_b32 (T12).
// Double-buffered async K/V staging, ONE barrier per step. Deferred softmax:
// P = exp2(s) (Q pre-scaled); fp32 partials + Lsum, normalized in combine.
__global__ __launch_bounds__(128, 1) void mqa_attn(const u16* __restrict__ Q,
                                                   const u16* __restrict__ Kmat,
                                                   const u16* __restrict__ Vt,
                                                   float* __restrict__ Oacc0,
                                                   float* __restrict__ Oacc1,
                                                   float* __restrict__ Lsum) {
    __shared__ __align__(16) u16 Ks[2][4 * 64 * 32];   // [buf][d-chunk][key64][32 d] 16KB/buf
    __shared__ __align__(16) u16 Vts[2][2 * 128 * 32]; // [buf][key-chunk][d128][32 k] 16KB/buf
    const int tid  = threadIdx.x;
    const int wave = tid >> 6, lane = tid & 63;
    const int l31 = lane & 31, hi = lane >> 5;
    const int h     = blockIdx.y;
    const int ksp   = blockIdx.z;
    const int qbase = blockIdx.x * 128 + wave * 64;
    const int kbase = ksp * 1024;

    // Q as B-operand frags: lane holds Q[q = qt*32 + l31][c*16 + hi*8 + j]
    bf16x8 qf[2][8];
#pragma unroll
    for (int qt = 0; qt < 2; ++qt) {
        const u16* qptr = Q + (size_t)(qbase + qt * 32 + l31) * 2048 + h * 128 + hi * 8;
#pragma unroll
        for (int c = 0; c < 8; ++c) qf[qt][c] = *(const bf16x8*)(qptr + c * 16);
    }

    f32x16 acc[2][4];
#pragma unroll
    for (int qt = 0; qt < 2; ++qt)
#pragma unroll
        for (int dt = 0; dt < 4; ++dt) acc[qt][dt] = (f32x16)(0.0f);
    float ls0 = 0.f, ls1 = 0.f;

    auto stage = [&](int s, int buf) {
        const int k0 = kbase + s * 64;
        // K tile: 1024 slots of 16B; 128 threads -> 8 iters
#pragma unroll
        for (int i = 0; i < 8; ++i) {
            const int slot = i * 128 + tid;
            const int kb4 = slot >> 8, win = slot & 255;
            const int row = win >> 2;
            GLOAD_LDS16(Kmat + (size_t)(k0 + row) * 128 + kb4 * 32 + sw_st(win & 3, row),
                        &Ks[buf][slot * 8]);
        }
        // V^T tile: 1024 slots
#pragma unroll
        for (int i = 0; i < 8; ++i) {
            const int slot = i * 128 + tid;
            const int kk = slot >> 9, win = slot & 511;
            const int row = win >> 2;
            GLOAD_LDS16(Vt + (size_t)row * VSTR + k0 + kk * 32 + sw_st(win & 3, row),
                        &Vts[buf][slot * 8]);
        }
    };

    stage(0, 0);
    __syncthreads();
    int cur = 0;

    for (int s = 0; s < 16; ++s) {
        if (s < 15) stage(s + 1, cur ^ 1);

        // ---- S^T = K Q^T per 32-key tile; P = exp2(S) packed in-register ----
        bf16x8 pa[2][4];  // [qt][key chunk of 16]
#pragma unroll
        for (int kt = 0; kt < 2; ++kt) {
            f32x16 sv0 = (f32x16)(0.0f), sv1 = (f32x16)(0.0f);
            const int row = kt * 32 + l31;  // key row this lane reads
#pragma unroll
            for (int c = 0; c < 8; ++c) {
                bf16x8 kf = *(const bf16x8*)&Ks[cur][(c >> 1) * 2048 + row * 32 +
                                                    sw_rd((c & 1) * 2 + hi, row)];
                sv0 = __builtin_amdgcn_mfma_f32_32x32x16_bf16(kf, qf[0][c], sv0, 0, 0, 0);
                sv1 = __builtin_amdgcn_mfma_f32_32x32x16_bf16(kf, qf[1][c], sv1, 0, 0, 0);
            }
            // lane holds S^T[key=(r&3)+8*(r>>2)+4*hi][q=l31] per q-tile
            float e0[16], e1[16];
#pragma unroll
            for (int r = 0; r < 16; ++r) {
                e0[r] = exp2f(sv0[r]); ls0 += e0[r];
                e1[r] = exp2f(sv1[r]); ls1 += e1[r];
            }
            // pack to bf16 + permlane32_swap -> A-frag keys ascending
#pragma unroll
            for (int half = 0; half < 2; ++half) {
                unsigned a0 = cvtpk(e0[half * 8 + 0], e0[half * 8 + 1]);
                unsigned a1 = cvtpk(e0[half * 8 + 2], e0[half * 8 + 3]);
                unsigned b0 = cvtpk(e0[half * 8 + 4], e0[half * 8 + 5]);
                unsigned b1 = cvtpk(e0[half * 8 + 6], e0[half * 8 + 7]);
                pl32swap(a0, b0);
                pl32swap(a1, b1);
                uint4_v w0 = {a0, a1, b0, b1};
                pa[0][kt * 2 + half] = __builtin_bit_cast(bf16x8, w0);

                unsigned c0 = cvtpk(e1[half * 8 + 0], e1[half * 8 + 1]);
                unsigned c1 = cvtpk(e1[half * 8 + 2], e1[half * 8 + 3]);
                unsigned d0 = cvtpk(e1[half * 8 + 4], e1[half * 8 + 5]);
                unsigned d1 = cvtpk(e1[half * 8 + 6], e1[half * 8 + 7]);
                pl32swap(c0, d0);
                pl32swap(c1, d1);
                uint4_v w1 = {c0, c1, d0, d1};
                pa[1][kt * 2 + half] = __builtin_bit_cast(bf16x8, w1);
            }
        }

        // ---- O += P V : 32 MFMA, each V-frag read feeds both q-tiles ----
#pragma unroll
        for (int kc = 0; kc < 4; ++kc) {
            const int ch = (kc & 1) * 2 + hi;
            const int kk = kc >> 1;
#pragma unroll
            for (int dt = 0; dt < 4; ++dt) {
                const int row = dt * 32 + l31;  // d row
                bf16x8 vf = *(const bf16x8*)&Vts[cur][kk * 4096 + row * 32 + sw_rd(ch, row)];
                acc[0][dt] = __builtin_amdgcn_mfma_f32_32x32x16_bf16(pa[0][kc], vf, acc[0][dt], 0, 0, 0);
                acc[1][dt] = __builtin_amdgcn_mfma_f32_32x32x16_bf16(pa[1][kc], vf, acc[1][dt], 0, 0, 0);
            }
        }
        __syncthreads();   // drains next-tile gload_lds + this tile's reads
        cur ^= 1;
    }

    // ---- epilogue: unnormalized fp32 partials + per-row sums ----
    float* __restrict__ Op = ksp ? Oacc1 : Oacc0;
#pragma unroll
    for (int qt = 0; qt < 2; ++qt) {
        float lrow = qt ? ls1 : ls0;
        lrow += __shfl_xor(lrow, 32);
        if (lane < 32)
            Lsum[(size_t)ksp * 32768 + h * 2048 + qbase + qt * 32 + l31] = lrow;
#pragma unroll
        for (int dt = 0; dt < 4; ++dt)
#pragma unroll
            for (int r = 0; r < 16; ++r) {
                const int qloc = (r & 3) + 8 * (r >> 2) + 4 * hi;
                Op[((size_t)h * 2048 + qbase + qt * 32 + qloc) * 128 + dt * 32 + l31] =
                    acc[qt][dt][r];
            }
    }
}

// combine: attn[q][h*128+d] = (O0+O1)/(L0+L1), bf16. One float4 per thread.
__global__ __launch_bounds__(256) void attn_combine(const float* __restrict__ O0,
                                                    const float* __restrict__ O1,
                                                    const float* __restrict__ L,
                                                    u16* __restrict__ attn) {
    const int f = blockIdx.x * 256 + threadIdx.x;  // [0, 1M)
    const int d4 = f & 31, h = (f >> 5) & 15, q = f >> 9;
    const int li = h * 2048 + q;
    const float inv = 1.0f / (L[li] + L[32768 + li]);
    const int oi = li * 32 + d4;
    const float4 a = ((const float4*)O0)[oi];
    const float4 b = ((const float4*)O1)[oi];
    ushort4 r;
    r.x = f2bf((a.x + b.x) * inv);
    r.y = f2bf((a.y + b.y) * inv);
    r.z = f2bf((a.z + b.z) * inv);
    r.w = f2bf((a.w + b.w) * inv);
    ((ushort4*)attn)[f] = r;
}

// ---------------- orchestration ----------------
extern "C" void kernel_launch(void* const* d_in, const int* in_sizes, int n_in,
                              void* d_out, int out_size, void* d_ws, size_t ws_size,
                              hipStream_t stream) {
    const float* x  = (const float*)d_in[0];
    const float* Wq = (const float*)d_in[1];
    const float* Wk = (const float*)d_in[2];
    const float* Wv = (const float*)d_in[3];
    const float* Wo = (const float*)d_in[4];
    float* out = (float*)d_out;

    // Wqb/Wkb/Wvb contiguous: together a 2304x2048 bf16 B matrix for gemm_qkv.
    // Overlays (stream-ordered, deterministic):
    //   Oacc0: [0,16MB)  -- xb+Wqb dead after gemm_qkv
    //   Oacc1: after attn buffer -- fresh scratch; Lsum after. Peak ~59MB.
    u16* ws   = (u16*)d_ws;
    u16* xb   = ws;                        // 2048x2048 bf16
    u16* Wqb  = xb  + (4 << 20);           // 2048x2048
    u16* Wkb  = Wqb + (4 << 20);           // 128x2048
    u16* Wvb  = Wkb + (256 << 10);         // 128x2048
    u16* Wob  = Wvb + (256 << 10);         // 2048x2048
    u16* qb   = Wob + (4 << 20);           // 2048x2048 (pre-scaled)
    u16* kb   = qb  + (4 << 20);           // 2048x128
    u16* vtb  = kb  + (256 << 10);         // 128xVSTR (V^T, padded rows)
    u16* attn = vtb + (512 << 10);         // 2048x2048 bf16
    float* Oacc0 = (float*)ws;             // 16 MB
    float* Oacc1 = (float*)(attn + (4 << 20));  // 16 MB
    float* Lsum  = Oacc1 + (4 << 20);      // 2 x 32768 fp32

    cast_all<<<12800, 256, 0, stream>>>(x, Wq, Wk, Wv, Wo, xb, Wqb, Wkb, Wvb, Wob);

    gemm_qkv<<<dim3(32, 18), 256, 0, stream>>>(xb, Wqb, qb, kb, vtb);
    mqa_attn<<<dim3(16, 16, 2), 128, 0, stream>>>(qb, kb, vtb, Oacc0, Oacc1, Lsum);
    attn_combine<<<4096, 256, 0, stream>>>(Oacc0, Oacc1, Lsum, attn);
    gemm_out<<<dim3(32, 16), 256, 0, stream>>>(attn, Wob, out);
}

// Round 11
// 213.819 us; speedup vs baseline: 1.4473x; 1.1165x over previous
//
#include <hip/hip_runtime.h>
#include <cmath>

typedef float    float4_t __attribute__((ext_vector_type(4)));
typedef float    f32x16   __attribute__((ext_vector_type(16)));
typedef __bf16   bf16x8   __attribute__((ext_vector_type(8)));
typedef unsigned uint4_v  __attribute__((ext_vector_type(4)));
typedef unsigned short u16;

// V^T row stride (u16 units): 2048 + 64 pad (keeps 16B alignment: 4224B rows).
#define VSTR 2112

// fp32 -> bf16 round-to-nearest-even
__device__ __forceinline__ u16 f2bf(float f) {
    unsigned u = __float_as_uint(f);
    u += 0x7fffu + ((u >> 16) & 1u);
    return (u16)(u >> 16);
}

// v_cvt_pk_bf16_f32: lo = bf16(a), hi = bf16(b)
__device__ __forceinline__ unsigned cvtpk(float a, float b) {
    unsigned r;
    asm("v_cvt_pk_bf16_f32 %0, %1, %2" : "=v"(r) : "v"(a), "v"(b));
    return r;
}
// v_permlane32_swap_b32: a[32..63] <-> b[0..31]
__device__ __forceinline__ void pl32swap(unsigned& a, unsigned& b) {
    asm volatile("v_permlane32_swap_b32 %0, %1" : "+v"(a), "+v"(b));
}

// async global->LDS, 16B per lane. LDS dest must be wave-uniform base + lane*16.
#define GLOAD_LDS16(g, l)                                              \
    __builtin_amdgcn_global_load_lds(                                  \
        (__attribute__((address_space(1))) void*)(g),                  \
        (__attribute__((address_space(3))) void*)(l), 16, 0, 0)

// Chunk swizzle: global chunk c of row r stored at LDS chunk (c + (r>>1))&3.
// Staging picks global chunk (cs - (r>>1))&3 for LDS slot cs; frag reads use
// chunk ((ch + (r>>1))&3). Keeps b128 frag reads near the free 2-way tier.
__device__ __forceinline__ int sw_st(int cs, int row) { return ((cs - (row >> 1)) & 3) * 8; }
__device__ __forceinline__ int sw_rd(int ch, int row) { return (((ch + (row >> 1)) & 3)) * 8; }

// ---------------- merged cast fp32 -> bf16 for all 5 tensors ----------------
__global__ __launch_bounds__(256) void cast_all(const float* __restrict__ x,
                                                const float* __restrict__ wq,
                                                const float* __restrict__ wk,
                                                const float* __restrict__ wv,
                                                const float* __restrict__ wo,
                                                u16* __restrict__ xb, u16* __restrict__ wqb,
                                                u16* __restrict__ wkb, u16* __restrict__ wvb,
                                                u16* __restrict__ wob) {
    const int b = blockIdx.x;
    const float* src;
    u16* dst;
    int i;
    if (b < 4096)      { src = x;  dst = xb;  i = b * 256 + threadIdx.x; }
    else if (b < 8192) { src = wq; dst = wqb; i = (b - 4096) * 256 + threadIdx.x; }
    else if (b < 8448) { src = wk; dst = wkb; i = (b - 8192) * 256 + threadIdx.x; }
    else if (b < 8704) { src = wv; dst = wvb; i = (b - 8448) * 256 + threadIdx.x; }
    else               { src = wo; dst = wob; i = (b - 8704) * 256 + threadIdx.x; }
    float4 f = ((const float4*)src)[i];
    ushort4 r;
    r.x = f2bf(f.x); r.y = f2bf(f.y); r.z = f2bf(f.z); r.w = f2bf(f.w);
    ((ushort4*)dst)[i] = r;
}

// ================= GEMM core (A @ B^T, 64x128 tile, BK=64, swizzled) ========
// 2-phase double-buffered staging; ONE barrier per K-step. 48KB LDS, 4 waves.
template <typename EPI>
__device__ __forceinline__ void gemm_core(const u16* __restrict__ A,
                                          const u16* __restrict__ B,
                                          int K, int bm, int bn, EPI epi) {
    __shared__ __align__(16) u16 As[2][2 * 64 * 32];
    __shared__ __align__(16) u16 Bs[2][2 * 128 * 32];
    const int tid  = threadIdx.x;
    const int lane = tid & 63, wave = tid >> 6;
    const int quad = lane >> 4, l16 = lane & 15;

    float4_t acc[4][2] = {};

    auto stage = [&](int k0, int buf) {
#pragma unroll
        for (int i = 0; i < 2; ++i) {
            const int slot = i * 256 + tid;
            const int ksb = slot >> 8, win = slot & 255;
            const int row = win >> 2;
            GLOAD_LDS16(A + (size_t)(bm + row) * K + k0 + ksb * 32 + sw_st(win & 3, row),
                        &As[buf][slot * 8]);
        }
#pragma unroll
        for (int i = 0; i < 4; ++i) {
            const int slot = i * 256 + tid;
            const int ksb = slot >> 9, win = slot & 511;
            const int row = win >> 2;
            GLOAD_LDS16(B + (size_t)(bn + row) * K + k0 + ksb * 32 + sw_st(win & 3, row),
                        &Bs[buf][slot * 8]);
        }
    };

    stage(0, 0);
    __syncthreads();
    int cur = 0;
    for (int k0 = 0; k0 < K; k0 += 64) {
        if (k0 + 64 < K) stage(k0 + 64, cur ^ 1);

        bf16x8 af[2][4], bfr[2][2];
#pragma unroll
        for (int ksb = 0; ksb < 2; ++ksb) {
#pragma unroll
            for (int mi = 0; mi < 4; ++mi) {
                const int rw = mi * 16 + l16;
                af[ksb][mi] = *(const bf16x8*)&As[cur][ksb * 2048 + rw * 32 + sw_rd(quad, rw)];
            }
#pragma unroll
            for (int ni = 0; ni < 2; ++ni) {
                const int rw = wave * 32 + ni * 16 + l16;
                bfr[ksb][ni] = *(const bf16x8*)&Bs[cur][ksb * 4096 + rw * 32 + sw_rd(quad, rw)];
            }
        }
#pragma unroll
        for (int mi = 0; mi < 4; ++mi)
#pragma unroll
            for (int ni = 0; ni < 2; ++ni) {
                acc[mi][ni] = __builtin_amdgcn_mfma_f32_16x16x32_bf16(
                    af[0][mi], bfr[0][ni], acc[mi][ni], 0, 0, 0);
                acc[mi][ni] = __builtin_amdgcn_mfma_f32_16x16x32_bf16(
                    af[1][mi], bfr[1][ni], acc[mi][ni], 0, 0, 0);
            }
        __syncthreads();   // drains next-tile gload_lds (vmcnt) + read hazard
        cur ^= 1;
    }

#pragma unroll
    for (int mi = 0; mi < 4; ++mi) {
        const int row = bm + mi * 16 + quad * 4;
#pragma unroll
        for (int ni = 0; ni < 2; ++ni) {
            const int col = bn + wave * 32 + ni * 16 + l16;
#pragma unroll
            for (int r = 0; r < 4; ++r) epi(row + r, col, acc[mi][ni][r]);
        }
    }
}

// Fused QKV projection: B rows = [Wq(2048) | Wk(128) | Wv(128)], N=2304.
// Q gets (1/sqrt(128))*log2(e) folded in (attention uses exp2).
__global__ __launch_bounds__(256) void gemm_qkv(const u16* __restrict__ A,
                                                const u16* __restrict__ B,
                                                u16* __restrict__ qb,
                                                u16* __restrict__ kb,
                                                u16* __restrict__ vtb) {
    gemm_core(A, B, 2048, blockIdx.x * 64, blockIdx.y * 128,
              [=](int row, int col, float v) {
                  if (col < 2048)
                      qb[(size_t)row * 2048 + col] = f2bf(v * 0.1275174313451427f);
                  else if (col < 2176)
                      kb[(size_t)row * 128 + (col - 2048)] = f2bf(v);
                  else
                      vtb[(size_t)(col - 2176) * VSTR + row] = f2bf(v);
              });
}

__global__ __launch_bounds__(256) void gemm_out(const u16* __restrict__ A,
                                                const u16* __restrict__ B,
                                                float* __restrict__ C) {
    gemm_core(A, B, 2048, blockIdx.x * 64, blockIdx.y * 128,
              [=](int row, int col, float v) {
                  C[(size_t)row * 2048 + col] = v;
              });
}

// ---------------- MQA flash attention, split-K=2, 64 keys/step --------------
// r8 post-mortem: 64q/wave at 4 waves/CU (1/SIMD) exposed every stall — dur 76us,
// MfmaUtil 17%, Occ 10%. Fix: back to r1's OCCUPANCY (256 threads, 4 waves/block,
// grid (16,16,2) -> 8 waves/CU = 2/SIMD, LDS 64KB = 2 blocks/CU) while KEEPING
// r3's per-wave structure: 32x32x16 swapped QK^T (A=K, B=Q => S^T col = query),
// P fully in-register via v_cvt_pk_bf16_f32 + v_permlane32_swap_b32 (T12) — no
// P-LDS round trip, ONE barrier/step. Each wave owns 32 q; QK is two independent
// 8-MFMA chains (kt interleaved) for intra-wave ILP; PV = 16 MFMA, 4 acc chains.
// Deferred softmax: P = exp2(s) (Q pre-scaled); fp32 partials + Lsum.
__global__ __launch_bounds__(256, 2) void mqa_attn(const u16* __restrict__ Q,
                                                   const u16* __restrict__ Kmat,
                                                   const u16* __restrict__ Vt,
                                                   float* __restrict__ Oacc0,
                                                   float* __restrict__ Oacc1,
                                                   float* __restrict__ Lsum) {
    __shared__ __align__(16) u16 Ks[2][4 * 64 * 32];   // [buf][d-chunk][key64][32 d] 16KB/buf
    __shared__ __align__(16) u16 Vts[2][2 * 128 * 32]; // [buf][key-chunk][d128][32 k] 16KB/buf
    const int tid  = threadIdx.x;
    const int wave = tid >> 6, lane = tid & 63;
    const int l31 = lane & 31, hi = lane >> 5;
    const int h     = blockIdx.y;
    const int ksp   = blockIdx.z;
    const int qbase = blockIdx.x * 128 + wave * 32;
    const int kbase = ksp * 1024;

    // Q as B-operand frags: lane holds Q[q = l31][c*16 + hi*8 + j]
    bf16x8 qf[8];
    {
        const u16* qptr = Q + (size_t)(qbase + l31) * 2048 + h * 128 + hi * 8;
#pragma unroll
        for (int c = 0; c < 8; ++c) qf[c] = *(const bf16x8*)(qptr + c * 16);
    }

    f32x16 acc[4];
#pragma unroll
    for (int dt = 0; dt < 4; ++dt) acc[dt] = (f32x16)(0.0f);
    float lsum = 0.f;

    auto stage = [&](int s, int buf) {
        const int k0 = kbase + s * 64;
        // K tile: 1024 slots of 16B; 256 threads -> 4 iters
#pragma unroll
        for (int i = 0; i < 4; ++i) {
            const int slot = i * 256 + tid;
            const int kb4 = slot >> 8, win = slot & 255;
            const int row = win >> 2;
            GLOAD_LDS16(Kmat + (size_t)(k0 + row) * 128 + kb4 * 32 + sw_st(win & 3, row),
                        &Ks[buf][slot * 8]);
        }
        // V^T tile: 1024 slots
#pragma unroll
        for (int i = 0; i < 4; ++i) {
            const int slot = i * 256 + tid;
            const int kk = slot >> 9, win = slot & 511;
            const int row = win >> 2;
            GLOAD_LDS16(Vt + (size_t)row * VSTR + k0 + kk * 32 + sw_st(win & 3, row),
                        &Vts[buf][slot * 8]);
        }
    };

    stage(0, 0);
    __syncthreads();
    int cur = 0;

    for (int s = 0; s < 16; ++s) {
        if (s < 15) stage(s + 1, cur ^ 1);

        // ---- S^T = K Q^T: two independent 8-MFMA chains (key tiles 0,1) ----
        f32x16 sv0 = (f32x16)(0.0f), sv1 = (f32x16)(0.0f);
        const int r0 = l31, r1 = 32 + l31;
#pragma unroll
        for (int c = 0; c < 8; ++c) {
            const int ch = (c & 1) * 2 + hi;
            const int base = (c >> 1) * 2048;
            bf16x8 kf0 = *(const bf16x8*)&Ks[cur][base + r0 * 32 + sw_rd(ch, r0)];
            bf16x8 kf1 = *(const bf16x8*)&Ks[cur][base + r1 * 32 + sw_rd(ch, r1)];
            sv0 = __builtin_amdgcn_mfma_f32_32x32x16_bf16(kf0, qf[c], sv0, 0, 0, 0);
            sv1 = __builtin_amdgcn_mfma_f32_32x32x16_bf16(kf1, qf[c], sv1, 0, 0, 0);
        }

        // ---- P = exp2(S) packed in-register -> PV A-frags ----
        bf16x8 pa[4];  // [key chunk of 16]
#pragma unroll
        for (int kt = 0; kt < 2; ++kt) {
            const f32x16& sv = kt ? sv1 : sv0;
            // lane holds S^T[key=(r&3)+8*(r>>2)+4*hi][q=l31]
            float e[16];
#pragma unroll
            for (int r = 0; r < 16; ++r) {
                e[r] = exp2f(sv[r]);
                lsum += e[r];
            }
            // pack to bf16 + permlane32_swap -> A-frag keys ascending
#pragma unroll
            for (int half = 0; half < 2; ++half) {
                unsigned a0 = cvtpk(e[half * 8 + 0], e[half * 8 + 1]);
                unsigned a1 = cvtpk(e[half * 8 + 2], e[half * 8 + 3]);
                unsigned b0 = cvtpk(e[half * 8 + 4], e[half * 8 + 5]);
                unsigned b1 = cvtpk(e[half * 8 + 6], e[half * 8 + 7]);
                pl32swap(a0, b0);
                pl32swap(a1, b1);
                uint4_v w = {a0, a1, b0, b1};
                pa[kt * 2 + half] = __builtin_bit_cast(bf16x8, w);
            }
        }

        // ---- O += P V : 16 MFMA, 4 independent dt chains ----
#pragma unroll
        for (int kc = 0; kc < 4; ++kc) {
            const int ch = (kc & 1) * 2 + hi;
            const int kk = kc >> 1;
#pragma unroll
            for (int dt = 0; dt < 4; ++dt) {
                const int row = dt * 32 + l31;  // d row
                bf16x8 vf = *(const bf16x8*)&Vts[cur][kk * 4096 + row * 32 + sw_rd(ch, row)];
                acc[dt] = __builtin_amdgcn_mfma_f32_32x32x16_bf16(pa[kc], vf, acc[dt], 0, 0, 0);
            }
        }
        __syncthreads();   // drains next-tile gload_lds + this tile's reads
        cur ^= 1;
    }

    // ---- epilogue: unnormalized fp32 partials + per-row sums ----
    float lrow = lsum + __shfl_xor(lsum, 32);
    float* __restrict__ Op = ksp ? Oacc1 : Oacc0;
    if (lane < 32) Lsum[(size_t)ksp * 32768 + h * 2048 + qbase + l31] = lrow;
#pragma unroll
    for (int dt = 0; dt < 4; ++dt)
#pragma unroll
        for (int r = 0; r < 16; ++r) {
            const int qloc = (r & 3) + 8 * (r >> 2) + 4 * hi;
            Op[((size_t)h * 2048 + qbase + qloc) * 128 + dt * 32 + l31] = acc[dt][r];
        }
}

// combine: attn[q][h*128+d] = (O0+O1)/(L0+L1), bf16. One float4 per thread.
__global__ __launch_bounds__(256) void attn_combine(const float* __restrict__ O0,
                                                    const float* __restrict__ O1,
                                                    const float* __restrict__ L,
                                                    u16* __restrict__ attn) {
    const int f = blockIdx.x * 256 + threadIdx.x;  // [0, 1M)
    const int d4 = f & 31, h = (f >> 5) & 15, q = f >> 9;
    const int li = h * 2048 + q;
    const float inv = 1.0f / (L[li] + L[32768 + li]);
    const int oi = li * 32 + d4;
    const float4 a = ((const float4*)O0)[oi];
    const float4 b = ((const float4*)O1)[oi];
    ushort4 r;
    r.x = f2bf((a.x + b.x) * inv);
    r.y = f2bf((a.y + b.y) * inv);
    r.z = f2bf((a.z + b.z) * inv);
    r.w = f2bf((a.w + b.w) * inv);
    ((ushort4*)attn)[f] = r;
}

// ---------------- orchestration ----------------
extern "C" void kernel_launch(void* const* d_in, const int* in_sizes, int n_in,
                              void* d_out, int out_size, void* d_ws, size_t ws_size,
                              hipStream_t stream) {
    const float* x  = (const float*)d_in[0];
    const float* Wq = (const float*)d_in[1];
    const float* Wk = (const float*)d_in[2];
    const float* Wv = (const float*)d_in[3];
    const float* Wo = (const float*)d_in[4];
    float* out = (float*)d_out;

    // Wqb/Wkb/Wvb contiguous: together a 2304x2048 bf16 B matrix for gemm_qkv.
    // Overlays (stream-ordered, deterministic):
    //   Oacc0: [0,16MB)  -- xb+Wqb dead after gemm_qkv
    //   Oacc1: after attn buffer -- fresh scratch; Lsum after. Peak ~59MB.
    u16* ws   = (u16*)d_ws;
    u16* xb   = ws;                        // 2048x2048 bf16
    u16* Wqb  = xb  + (4 << 20);           // 2048x2048
    u16* Wkb  = Wqb + (4 << 20);           // 128x2048
    u16* Wvb  = Wkb + (256 << 10);         // 128x2048
    u16* Wob  = Wvb + (256 << 10);         // 2048x2048
    u16* qb   = Wob + (4 << 20);           // 2048x2048 (pre-scaled)
    u16* kb   = qb  + (4 << 20);           // 2048x128
    u16* vtb  = kb  + (256 << 10);         // 128xVSTR (V^T, padded rows)
    u16* attn = vtb + (512 << 10);         // 2048x2048 bf16
    float* Oacc0 = (float*)ws;             // 16 MB
    float* Oacc1 = (float*)(attn + (4 << 20));  // 16 MB
    float* Lsum  = Oacc1 + (4 << 20);      // 2 x 32768 fp32

    cast_all<<<12800, 256, 0, stream>>>(x, Wq, Wk, Wv, Wo, xb, Wqb, Wkb, Wvb, Wob);

    gemm_qkv<<<dim3(32, 18), 256, 0, stream>>>(xb, Wqb, qb, kb, vtb);
    mqa_attn<<<dim3(16, 16, 2), 256, 0, stream>>>(qb, kb, vtb, Oacc0, Oacc1, Lsum);
    attn_combine<<<4096, 256, 0, stream>>>(Oacc0, Oacc1, Lsum, attn);
    gemm_out<<<dim3(32, 16), 256, 0, stream>>>(attn, Wob, out);
}